// Round 1
// baseline (571.213 us; speedup 1.0000x reference)
//
#include <hip/hip_runtime.h>

#define TT 4
#define BB 64
#define CC 64
#define PP 1024
#define NN 256
#define EE 8

// 1/sqrt(1+1e-5)
#define RSQ 0.99999500003749975f

static __device__ __forceinline__ float rfl_f(float v) {
    return __uint_as_float(__builtin_amdgcn_readfirstlane(__float_as_uint(v)));
}

// ---------------- Kernel 1: router LIF + spike spatial mean ----------------
// grid: B*C blocks, 256 threads. Each block: one (b,c), 1024 pixels.
__global__ void k_router_lif(const float* __restrict__ x, float* __restrict__ mean_spk) {
    int bc = blockIdx.x;
    int b = bc >> 6, c = bc & 63;
    int tid = threadIdx.x;
    float cnt0 = 0.f, cnt1 = 0.f, cnt2 = 0.f, cnt3 = 0.f;
    const size_t tstride = (size_t)BB * CC * PP;
    #pragma unroll
    for (int k = 0; k < 4; ++k) {
        int p = tid + (k << 8);
        const float* xp = x + ((size_t)b * CC + c) * PP + p;
        float v = 0.f, xt, sp;
        xt = xp[0];
        v += (xt - v) * 0.5f;
        sp = (v >= 1.f) ? 1.f : 0.f; cnt0 += sp; v = (v >= 1.f) ? 0.f : v;
        xt = xp[tstride];
        v += (xt - v) * 0.5f;
        sp = (v >= 1.f) ? 1.f : 0.f; cnt1 += sp; v = (v >= 1.f) ? 0.f : v;
        xt = xp[2 * tstride];
        v += (xt - v) * 0.5f;
        sp = (v >= 1.f) ? 1.f : 0.f; cnt2 += sp; v = (v >= 1.f) ? 0.f : v;
        xt = xp[3 * tstride];
        v += (xt - v) * 0.5f;
        sp = (v >= 1.f) ? 1.f : 0.f; cnt3 += sp; v = (v >= 1.f) ? 0.f : v;
    }
    // block reduce (4 waves)
    __shared__ float red[4][4];
    int lane = tid & 63, wv = tid >> 6;
    #pragma unroll
    for (int off = 32; off > 0; off >>= 1) {
        cnt0 += __shfl_down(cnt0, off, 64);
        cnt1 += __shfl_down(cnt1, off, 64);
        cnt2 += __shfl_down(cnt2, off, 64);
        cnt3 += __shfl_down(cnt3, off, 64);
    }
    if (lane == 0) { red[wv][0] = cnt0; red[wv][1] = cnt1; red[wv][2] = cnt2; red[wv][3] = cnt3; }
    __syncthreads();
    if (tid < 4) {
        float s = red[0][tid] + red[1][tid] + red[2][tid] + red[3][tid];
        mean_spk[((size_t)tid * BB + b) * CC + c] = s * (1.f / 1024.f);
    }
}

// ---------------- Kernel: prep (fold BN into weights, transpose to [e][c][o]) --------
__global__ void k_prep(const float* __restrict__ w1, const float* __restrict__ b1,
                       const float* __restrict__ g1, const float* __restrict__ be1,
                       const float* __restrict__ w2, const float* __restrict__ b2,
                       const float* __restrict__ g2, const float* __restrict__ be2,
                       float* __restrict__ w1t, float* __restrict__ w2t,
                       float* __restrict__ fb1, float* __restrict__ fb2) {
    int idx = blockIdx.x * 256 + threadIdx.x;
    if (idx < EE * CC * CC) {
        int e = idx >> 12, rem = idx & 4095;
        int c = rem >> 6, o = rem & 63;
        float s1 = g1[e * 64 + o] * RSQ;
        float s2 = g2[e * 64 + o] * RSQ;
        w1t[idx] = w1[(e * 64 + o) * 64 + c] * s1;
        w2t[idx] = w2[(e * 64 + o) * 64 + c] * s2;
    }
    if (idx < EE * CC) {
        fb1[idx] = b1[idx] * (g1[idx] * RSQ) + be1[idx];
        fb2[idx] = b2[idx] * (g2[idx] * RSQ) + be2[idx];
    }
}

// ---------------- Kernel 2: router logits + softmax + top2 -> combine ----------------
__global__ void k_router(const float* __restrict__ mean_spk, const float* __restrict__ rw,
                         const float* __restrict__ rb, const float* __restrict__ rg,
                         const float* __restrict__ rbe, float* __restrict__ combine) {
    int n = threadIdx.x;
    if (n >= NN) return;
    float l[EE];
    #pragma unroll
    for (int e = 0; e < EE; ++e) {
        float acc = 0.f;
        for (int c = 0; c < CC; ++c)
            acc = fmaf(mean_spk[n * CC + c], rw[e * CC + c], acc);
        l[e] = (acc + rb[e]) * (rg[e] * RSQ) + rbe[e];
    }
    float m = l[0];
    #pragma unroll
    for (int e = 1; e < EE; ++e) m = fmaxf(m, l[e]);
    float pr[EE], s = 0.f;
    #pragma unroll
    for (int e = 0; e < EE; ++e) { pr[e] = expf(l[e] - m); s += pr[e]; }
    #pragma unroll
    for (int e = 0; e < EE; ++e) pr[e] = pr[e] / s;
    int i1 = 0; float v1 = pr[0];
    #pragma unroll
    for (int e = 1; e < EE; ++e) { if (pr[e] > v1) { v1 = pr[e]; i1 = e; } }
    int i2 = (i1 == 0) ? 1 : 0; float v2 = (i1 == 0) ? pr[1] : pr[0];
    #pragma unroll
    for (int e = 0; e < EE; ++e) { if (e != i1 && pr[e] > v2) { v2 = pr[e]; i2 = e; } }
    float wsum = v1 + v2;
    float wa = v1 / wsum, wb = v2 / wsum;
    #pragma unroll
    for (int e = 0; e < EE; ++e)
        combine[n * EE + e] = (e == i1) ? wa : ((e == i2) ? wb : 0.f);
}

// ---------------- Kernel 3: experts (binary-input conv, scalar-broadcast weights) ----
template <bool FIRST>
static __device__ __forceinline__ void expert_pass(
    const float* __restrict__ xn, int p,
    const float* __restrict__ wt1, const float* __restrict__ wt2,
    const float* __restrict__ f1, const float* __restrict__ f2,
    float tau, float wexp, float wsum1,
    unsigned long long m1, float (&acc)[64])
{
    float h[64];
    #pragma unroll
    for (int o = 0; o < 64; ++o) h[o] = 0.f;

    // conv1: h[o] = sum_c s1[c] * w1t[c][o]
    #pragma unroll 2
    for (int c = 0; c < 64; ++c) {
        float bf = (float)((unsigned)(m1 >> c) & 1u);
        const float* __restrict__ wr = wt1 + (c << 6);
        #pragma unroll
        for (int o = 0; o < 64; ++o) h[o] = fmaf(bf, wr[o], h[o]);
    }

    // BN fold + build s2 mask; stash BN(h); init output accumulator
    unsigned long long m2 = 0ull;
    #pragma unroll
    for (int o = 0; o < 64; ++o) {
        float xo = xn[o * PP + p];
        float bnh = h[o] + f1[o];
        if (FIRST) acc[o] = xo * wsum1;
        float x2 = xo + bnh;
        h[o] = bnh;
        m2 |= (unsigned long long)(x2 >= tau) << o;
    }

    // conv2 accumulates into h (pre-scaled weights)
    #pragma unroll 2
    for (int c = 0; c < 64; ++c) {
        float bf = (float)((unsigned)(m2 >> c) & 1u);
        const float* __restrict__ wr = wt2 + (c << 6);
        #pragma unroll
        for (int o = 0; o < 64; ++o) h[o] = fmaf(bf, wr[o], h[o]);
    }

    #pragma unroll
    for (int o = 0; o < 64; ++o) acc[o] = fmaf(wexp, h[o] + f2[o], acc[o]);
}

__global__ void __launch_bounds__(64, 2) k_experts(
    const float* __restrict__ x, const float* __restrict__ combine,
    const float* __restrict__ w1t, const float* __restrict__ w2t,
    const float* __restrict__ fb1, const float* __restrict__ fb2,
    float* __restrict__ out)
{
    int blk = blockIdx.x;
    int n = blk >> 4;            // token
    int g = blk & 15;            // pixel group (64 px)
    int lane = threadIdx.x;      // lane = pixel
    int p = (g << 6) + lane;
    const float* __restrict__ xn = x + (size_t)n * (CC * PP);

    // uniform top-2 expert scan
    int e1 = -1, e2 = -1; float wAv = 0.f, wBv = 0.f;
    #pragma unroll
    for (int e = 0; e < EE; ++e) {
        float w = combine[n * EE + e];
        bool nz = (w != 0.f);
        if (nz && e1 < 0) { e1 = e; wAv = w; }
        else if (nz && e2 < 0) { e2 = e; wBv = w; }
    }
    if (e1 < 0) { e1 = 0; wAv = 0.f; }
    if (e2 < 0) { e2 = e1; wBv = 0.f; }
    e1 = __builtin_amdgcn_readfirstlane(e1);
    e2 = __builtin_amdgcn_readfirstlane(e2);
    wAv = rfl_f(wAv); wBv = rfl_f(wBv);
    float tauA = (float)(1.5 + 2.5 * (double)e1 / 7.0);
    float tauB = (float)(1.5 + 2.5 * (double)e2 / 7.0);
    float wsum1 = 1.f + wAv + wBv;

    // s1 masks for both experts (one pass over x)
    unsigned long long mA = 0ull, mB = 0ull;
    #pragma unroll
    for (int c = 0; c < 64; ++c) {
        float xv = xn[c * PP + p];
        mA |= (unsigned long long)(xv >= tauA) << c;
        mB |= (unsigned long long)(xv >= tauB) << c;
    }

    float acc[64];
    expert_pass<true >(xn, p, w1t + (e1 << 12), w2t + (e1 << 12),
                       fb1 + (e1 << 6), fb2 + (e1 << 6), tauA, wAv, wsum1, mA, acc);
    expert_pass<false>(xn, p, w1t + (e2 << 12), w2t + (e2 << 12),
                       fb1 + (e2 << 6), fb2 + (e2 << 6), tauB, wBv, wsum1, mB, acc);

    float* __restrict__ on = out + (size_t)n * (CC * PP);
    #pragma unroll
    for (int o = 0; o < 64; ++o) on[o * PP + p] = acc[o];
}

extern "C" void kernel_launch(void* const* d_in, const int* in_sizes, int n_in,
                              void* d_out, int out_size, void* d_ws, size_t ws_size,
                              hipStream_t stream) {
    const float* x   = (const float*)d_in[0];
    const float* w1  = (const float*)d_in[1];
    const float* b1  = (const float*)d_in[2];
    const float* g1  = (const float*)d_in[3];
    const float* be1 = (const float*)d_in[4];
    const float* w2  = (const float*)d_in[5];
    const float* b2  = (const float*)d_in[6];
    const float* g2  = (const float*)d_in[7];
    const float* be2 = (const float*)d_in[8];
    const float* rw  = (const float*)d_in[9];
    const float* rb  = (const float*)d_in[10];
    const float* rg  = (const float*)d_in[11];
    const float* rbe = (const float*)d_in[12];
    float* out = (float*)d_out;
    float* ws  = (float*)d_ws;

    float* mean_spk = ws;              // 16384
    float* combine  = ws + 16384;      // 2048
    float* w1t      = ws + 18432;      // 32768
    float* w2t      = ws + 51200;      // 32768
    float* fb1      = ws + 83968;      // 512
    float* fb2      = ws + 84480;      // 512  (total 84992 floats)

    hipLaunchKernelGGL(k_router_lif, dim3(BB * CC), dim3(256), 0, stream, x, mean_spk);
    hipLaunchKernelGGL(k_prep, dim3(128), dim3(256), 0, stream,
                       w1, b1, g1, be1, w2, b2, g2, be2, w1t, w2t, fb1, fb2);
    hipLaunchKernelGGL(k_router, dim3(1), dim3(256), 0, stream,
                       mean_spk, rw, rb, rg, rbe, combine);
    hipLaunchKernelGGL(k_experts, dim3(NN * 16), dim3(64), 0, stream,
                       x, combine, w1t, w2t, fb1, fb2, out);
}

// Round 2
// 139.083 us; speedup vs baseline: 4.1070x; 4.1070x over previous
//
#include <hip/hip_runtime.h>
#include <hip/hip_bf16.h>

#define TT 4
#define BB 64
#define CC 64
#define PP 1024
#define NN 256
#define EE 8

// 1/sqrt(1+1e-5)
#define RSQ 0.99999500003749975f

typedef __attribute__((ext_vector_type(8))) short short8;
typedef __attribute__((ext_vector_type(4))) float f32x4;

static __device__ __forceinline__ float rfl_f(float v) {
    return __uint_as_float(__builtin_amdgcn_readfirstlane(__float_as_uint(v)));
}
static __device__ __forceinline__ unsigned short f2bf(float v) {
    __hip_bfloat16 h = __float2bfloat16(v);
    return *reinterpret_cast<unsigned short*>(&h);
}

// ---------------- Kernel 1: router LIF + spike spatial mean ----------------
__global__ void k_router_lif(const float* __restrict__ x, float* __restrict__ mean_spk) {
    int bc = blockIdx.x;
    int b = bc >> 6, c = bc & 63;
    int tid = threadIdx.x;
    float cnt0 = 0.f, cnt1 = 0.f, cnt2 = 0.f, cnt3 = 0.f;
    const size_t tstride = (size_t)BB * CC * PP;
    #pragma unroll
    for (int k = 0; k < 4; ++k) {
        int p = tid + (k << 8);
        const float* xp = x + ((size_t)b * CC + c) * PP + p;
        float v = 0.f, xt, sp;
        xt = xp[0];
        v += (xt - v) * 0.5f;
        sp = (v >= 1.f) ? 1.f : 0.f; cnt0 += sp; v = (v >= 1.f) ? 0.f : v;
        xt = xp[tstride];
        v += (xt - v) * 0.5f;
        sp = (v >= 1.f) ? 1.f : 0.f; cnt1 += sp; v = (v >= 1.f) ? 0.f : v;
        xt = xp[2 * tstride];
        v += (xt - v) * 0.5f;
        sp = (v >= 1.f) ? 1.f : 0.f; cnt2 += sp; v = (v >= 1.f) ? 0.f : v;
        xt = xp[3 * tstride];
        v += (xt - v) * 0.5f;
        sp = (v >= 1.f) ? 1.f : 0.f; cnt3 += sp; v = (v >= 1.f) ? 0.f : v;
    }
    __shared__ float red[4][4];
    int lane = tid & 63, wv = tid >> 6;
    #pragma unroll
    for (int off = 32; off > 0; off >>= 1) {
        cnt0 += __shfl_down(cnt0, off, 64);
        cnt1 += __shfl_down(cnt1, off, 64);
        cnt2 += __shfl_down(cnt2, off, 64);
        cnt3 += __shfl_down(cnt3, off, 64);
    }
    if (lane == 0) { red[wv][0] = cnt0; red[wv][1] = cnt1; red[wv][2] = cnt2; red[wv][3] = cnt3; }
    __syncthreads();
    if (tid < 4) {
        float s = red[0][tid] + red[1][tid] + red[2][tid] + red[3][tid];
        mean_spk[((size_t)tid * BB + b) * CC + c] = s * (1.f / 1024.f);
    }
}

// ---------------- prep: fold BN into bf16 weights, layout [e][conv][o][c] ----------
__global__ void k_prep(const float* __restrict__ w1, const float* __restrict__ b1,
                       const float* __restrict__ g1, const float* __restrict__ be1,
                       const float* __restrict__ w2, const float* __restrict__ b2,
                       const float* __restrict__ g2, const float* __restrict__ be2,
                       unsigned short* __restrict__ wb,
                       float* __restrict__ fb1, float* __restrict__ fb2) {
    int idx = blockIdx.x * 256 + threadIdx.x;
    if (idx < EE * CC * CC) {
        int e = idx >> 12, rem = idx & 4095;
        int o = rem >> 6;
        float s1 = g1[e * 64 + o] * RSQ;
        float s2 = g2[e * 64 + o] * RSQ;
        wb[(e * 2 + 0) * 4096 + rem] = f2bf(w1[idx] * s1);
        wb[(e * 2 + 1) * 4096 + rem] = f2bf(w2[idx] * s2);
    }
    if (idx < EE * CC) {
        fb1[idx] = b1[idx] * (g1[idx] * RSQ) + be1[idx];
        fb2[idx] = b2[idx] * (g2[idx] * RSQ) + be2[idx];
    }
}

// ---------------- Kernel 2: router logits + softmax + top2 -> combine ----------------
__global__ void k_router(const float* __restrict__ mean_spk, const float* __restrict__ rw,
                         const float* __restrict__ rb, const float* __restrict__ rg,
                         const float* __restrict__ rbe, float* __restrict__ combine) {
    int n = threadIdx.x;
    if (n >= NN) return;
    float l[EE];
    #pragma unroll
    for (int e = 0; e < EE; ++e) {
        float acc = 0.f;
        for (int c = 0; c < CC; ++c)
            acc = fmaf(mean_spk[n * CC + c], rw[e * CC + c], acc);
        l[e] = (acc + rb[e]) * (rg[e] * RSQ) + rbe[e];
    }
    float m = l[0];
    #pragma unroll
    for (int e = 1; e < EE; ++e) m = fmaxf(m, l[e]);
    float pr[EE], s = 0.f;
    #pragma unroll
    for (int e = 0; e < EE; ++e) { pr[e] = expf(l[e] - m); s += pr[e]; }
    #pragma unroll
    for (int e = 0; e < EE; ++e) pr[e] = pr[e] / s;
    int i1 = 0; float v1 = pr[0];
    #pragma unroll
    for (int e = 1; e < EE; ++e) { if (pr[e] > v1) { v1 = pr[e]; i1 = e; } }
    int i2 = (i1 == 0) ? 1 : 0; float v2 = (i1 == 0) ? pr[1] : pr[0];
    #pragma unroll
    for (int e = 0; e < EE; ++e) { if (e != i1 && pr[e] > v2) { v2 = pr[e]; i2 = e; } }
    float wsum = v1 + v2;
    float wa = v1 / wsum, wb2 = v2 / wsum;
    #pragma unroll
    for (int e = 0; e < EE; ++e)
        combine[n * EE + e] = (e == i1) ? wa : ((e == i2) ? wb2 : 0.f);
}

// ---------------- Kernel 3: experts via MFMA ----------------
// Block = token n, 256-px chunk; 4 waves, each owns 64 px x 64 out-ch.
// mfma_f32_16x16x32_bf16 layouts:
//   A[i][k]: i = lane%16, k = 8*(lane/16)+j   (j=0..7)
//   B[k][j]: j = lane%16, k = 8*(lane/16)+j
//   D[i][j]: j = lane%16, i = 4*(lane/16)+reg
static __device__ __forceinline__ void run_expert(
    const float* __restrict__ xn, const unsigned short* __restrict__ wbe,
    const float* __restrict__ f1e, const float* __restrict__ f2e,
    float tau, int P0, int l16, int g,
    unsigned short* __restrict__ s2w,   // wave-private LDS: [64 px][72]
    f32x4 (&acc)[4][4])
{
    #pragma unroll
    for (int tm = 0; tm < 4; ++tm)
        #pragma unroll
        for (int tn = 0; tn < 4; ++tn)
            acc[tm][tn] = (f32x4){0.f, 0.f, 0.f, 0.f};

    // ---- conv1: A = spike(x>=tau), B = weights ----
    #pragma unroll
    for (int ks = 0; ks < 2; ++ks) {
        short8 bfr[4];
        #pragma unroll
        for (int tn = 0; tn < 4; ++tn)
            bfr[tn] = *(const short8*)(wbe + ((l16 + 16 * tn) * 64 + ks * 32 + g * 8));
        #pragma unroll
        for (int tm = 0; tm < 4; ++tm) {
            const float* xp = xn + (size_t)(ks * 32 + g * 8) * PP + (P0 + tm * 16 + l16);
            short8 a;
            #pragma unroll
            for (int j = 0; j < 8; ++j)
                a[j] = (xp[j * PP] >= tau) ? (short)0x3F80 : (short)0;
            #pragma unroll
            for (int tn = 0; tn < 4; ++tn)
                acc[tm][tn] = __builtin_amdgcn_mfma_f32_16x16x32_bf16(a, bfr[tn], acc[tm][tn], 0, 0, 0);
        }
    }

    // ---- bias, x2 = x + bn(h1), s2 mask -> LDS; fold f1+f2 into acc ----
    #pragma unroll
    for (int tn = 0; tn < 4; ++tn) {
        int ch = l16 + 16 * tn;
        float f1v = f1e[ch];
        float f2v = f2e[ch];
        #pragma unroll
        for (int tm = 0; tm < 4; ++tm) {
            int pxl = tm * 16 + g * 4;  // local px of reg 0
            f32x4 xv = *(const f32x4*)(xn + (size_t)ch * PP + (P0 + pxl));
            #pragma unroll
            for (int r = 0; r < 4; ++r) {
                float bnh = acc[tm][tn][r] + f1v;
                float x2 = xv[r] + bnh;
                s2w[(pxl + r) * 72 + ch] = (x2 >= tau) ? (unsigned short)0x3F80 : (unsigned short)0;
                acc[tm][tn][r] = bnh + f2v;
            }
        }
    }

    // ---- conv2: A = s2 from LDS, accumulate into acc ----
    #pragma unroll
    for (int ks = 0; ks < 2; ++ks) {
        short8 bfr[4];
        #pragma unroll
        for (int tn = 0; tn < 4; ++tn)
            bfr[tn] = *(const short8*)(wbe + 4096 + ((l16 + 16 * tn) * 64 + ks * 32 + g * 8));
        #pragma unroll
        for (int tm = 0; tm < 4; ++tm) {
            short8 a = *(const short8*)(s2w + (tm * 16 + l16) * 72 + ks * 32 + g * 8);
            #pragma unroll
            for (int tn = 0; tn < 4; ++tn)
                acc[tm][tn] = __builtin_amdgcn_mfma_f32_16x16x32_bf16(a, bfr[tn], acc[tm][tn], 0, 0, 0);
        }
    }
}

__global__ void __launch_bounds__(256) k_experts(
    const float* __restrict__ x, const float* __restrict__ combine,
    const unsigned short* __restrict__ wb,
    const float* __restrict__ fb1, const float* __restrict__ fb2,
    float* __restrict__ out)
{
    __shared__ unsigned short s2[4][64 * 72];  // 36,864 B

    int blk = blockIdx.x;
    int n = blk >> 2;
    int chunk = blk & 3;
    int tid = threadIdx.x;
    int wv = tid >> 6;
    int lane = tid & 63;
    int l16 = lane & 15;
    int g = lane >> 4;
    int P0 = chunk * 256 + wv * 64;  // wave's pixel base within token

    const float* __restrict__ xn = x + (size_t)n * (CC * PP);

    // uniform top-2 expert scan
    int e1 = -1, e2 = -1; float wAv = 0.f, wBv = 0.f;
    #pragma unroll
    for (int e = 0; e < EE; ++e) {
        float w = combine[n * EE + e];
        bool nz = (w != 0.f);
        if (nz && e1 < 0) { e1 = e; wAv = w; }
        else if (nz && e2 < 0) { e2 = e; wBv = w; }
    }
    if (e1 < 0) { e1 = 0; wAv = 0.f; }
    if (e2 < 0) { e2 = (e1 == 0) ? 1 : 0; wBv = 0.f; }
    e1 = __builtin_amdgcn_readfirstlane(e1);
    e2 = __builtin_amdgcn_readfirstlane(e2);
    wAv = rfl_f(wAv); wBv = rfl_f(wBv);
    float tauA = (float)(1.5 + 2.5 * (double)e1 / 7.0);
    float tauB = (float)(1.5 + 2.5 * (double)e2 / 7.0);
    float wsum1 = 1.f + wAv + wBv;

    f32x4 accA[4][4], accB[4][4];
    run_expert(xn, wb + e1 * 8192, fb1 + e1 * 64, fb2 + e1 * 64,
               tauA, P0, l16, g, &s2[wv][0], accA);
    run_expert(xn, wb + e2 * 8192, fb1 + e2 * 64, fb2 + e2 * 64,
               tauB, P0, l16, g, &s2[wv][0], accB);

    // ---- final: out = x*(1+wA+wB) + wA*accA + wB*accB ----
    float* __restrict__ on = out + (size_t)n * (CC * PP);
    #pragma unroll
    for (int tn = 0; tn < 4; ++tn) {
        int ch = l16 + 16 * tn;
        #pragma unroll
        for (int tm = 0; tm < 4; ++tm) {
            int pxb = P0 + tm * 16 + g * 4;
            f32x4 xv = *(const f32x4*)(xn + (size_t)ch * PP + pxb);
            f32x4 o;
            #pragma unroll
            for (int r = 0; r < 4; ++r)
                o[r] = fmaf(xv[r], wsum1, fmaf(wAv, accA[tm][tn][r], wBv * accB[tm][tn][r]));
            *(f32x4*)(on + (size_t)ch * PP + pxb) = o;
        }
    }
}

extern "C" void kernel_launch(void* const* d_in, const int* in_sizes, int n_in,
                              void* d_out, int out_size, void* d_ws, size_t ws_size,
                              hipStream_t stream) {
    const float* x   = (const float*)d_in[0];
    const float* w1  = (const float*)d_in[1];
    const float* b1  = (const float*)d_in[2];
    const float* g1  = (const float*)d_in[3];
    const float* be1 = (const float*)d_in[4];
    const float* w2  = (const float*)d_in[5];
    const float* b2  = (const float*)d_in[6];
    const float* g2  = (const float*)d_in[7];
    const float* be2 = (const float*)d_in[8];
    const float* rw  = (const float*)d_in[9];
    const float* rb  = (const float*)d_in[10];
    const float* rg  = (const float*)d_in[11];
    const float* rbe = (const float*)d_in[12];
    float* out = (float*)d_out;
    float* ws  = (float*)d_ws;

    float* mean_spk     = ws;               // 16384 floats
    float* combine      = ws + 16384;       // 2048
    unsigned short* wb  = (unsigned short*)(ws + 18432);  // 65536 ushorts = 32768 floats
    float* fb1          = ws + 51200;       // 512
    float* fb2          = ws + 51712;       // 512  (total 52224 floats)

    hipLaunchKernelGGL(k_router_lif, dim3(BB * CC), dim3(256), 0, stream, x, mean_spk);
    hipLaunchKernelGGL(k_prep, dim3(128), dim3(256), 0, stream,
                       w1, b1, g1, be1, w2, b2, g2, be2, wb, fb1, fb2);
    hipLaunchKernelGGL(k_router, dim3(1), dim3(256), 0, stream,
                       mean_spk, rw, rb, rg, rbe, combine);
    hipLaunchKernelGGL(k_experts, dim3(NN * 4), dim3(256), 0, stream,
                       x, combine, wb, fb1, fb2, out);
}

// Round 3
// 102.031 us; speedup vs baseline: 5.5984x; 1.3631x over previous
//
#include <hip/hip_runtime.h>
#include <hip/hip_bf16.h>

#define TT 4
#define BB 64
#define CC 64
#define PP 1024
#define NN 256
#define EE 8

// 1/sqrt(1+1e-5)
#define RSQ 0.99999500003749975f

typedef __attribute__((ext_vector_type(8))) short short8;
typedef __attribute__((ext_vector_type(4))) float f32x4;

static __device__ __forceinline__ float rfl_f(float v) {
    return __uint_as_float(__builtin_amdgcn_readfirstlane(__float_as_uint(v)));
}
static __device__ __forceinline__ unsigned short f2bf(float v) {
    __hip_bfloat16 h = __float2bfloat16(v);
    return *reinterpret_cast<unsigned short*>(&h);
}

// ---------------- Kernel 1: router LIF + spike spatial mean (f32x4) ----------------
__global__ void k_router_lif(const float* __restrict__ x, float* __restrict__ mean_spk) {
    int bc = blockIdx.x;
    int b = bc >> 6, c = bc & 63;
    int tid = threadIdx.x;
    const size_t tstride = (size_t)BB * CC * PP;
    const float* xp = x + ((size_t)b * CC + c) * PP + tid * 4;
    f32x4 v = {0.f, 0.f, 0.f, 0.f};
    float cnt[4];
    #pragma unroll
    for (int t = 0; t < 4; ++t) {
        f32x4 xt = *(const f32x4*)(xp + t * tstride);
        float cc = 0.f;
        #pragma unroll
        for (int r = 0; r < 4; ++r) {
            v[r] += (xt[r] - v[r]) * 0.5f;
            bool s = v[r] >= 1.f;
            cc += s ? 1.f : 0.f;
            v[r] = s ? 0.f : v[r];
        }
        cnt[t] = cc;
    }
    __shared__ float red[4][4];
    int lane = tid & 63, wv = tid >> 6;
    #pragma unroll
    for (int off = 32; off > 0; off >>= 1) {
        cnt[0] += __shfl_down(cnt[0], off, 64);
        cnt[1] += __shfl_down(cnt[1], off, 64);
        cnt[2] += __shfl_down(cnt[2], off, 64);
        cnt[3] += __shfl_down(cnt[3], off, 64);
    }
    if (lane == 0) { red[wv][0] = cnt[0]; red[wv][1] = cnt[1]; red[wv][2] = cnt[2]; red[wv][3] = cnt[3]; }
    __syncthreads();
    if (tid < 4) {
        float s = red[0][tid] + red[1][tid] + red[2][tid] + red[3][tid];
        mean_spk[((size_t)tid * BB + b) * CC + c] = s * (1.f / 1024.f);
    }
}

// ---------------- prep: fold BN into bf16 weights, layout [e][conv][o][c] ----------
__global__ void k_prep(const float* __restrict__ w1, const float* __restrict__ b1,
                       const float* __restrict__ g1, const float* __restrict__ be1,
                       const float* __restrict__ w2, const float* __restrict__ b2,
                       const float* __restrict__ g2, const float* __restrict__ be2,
                       unsigned short* __restrict__ wb,
                       float* __restrict__ fb1, float* __restrict__ fb2) {
    int idx = blockIdx.x * 256 + threadIdx.x;
    if (idx < EE * CC * CC) {
        int e = idx >> 12, rem = idx & 4095;
        int o = rem >> 6;
        float s1 = g1[e * 64 + o] * RSQ;
        float s2 = g2[e * 64 + o] * RSQ;
        wb[(e * 2 + 0) * 4096 + rem] = f2bf(w1[idx] * s1);
        wb[(e * 2 + 1) * 4096 + rem] = f2bf(w2[idx] * s2);
    }
    if (idx < EE * CC) {
        fb1[idx] = b1[idx] * (g1[idx] * RSQ) + be1[idx];
        fb2[idx] = b2[idx] * (g2[idx] * RSQ) + be2[idx];
    }
}

// ---------------- Kernel 2: router logits + softmax + top2 -> combine ----------------
__global__ void k_router(const float* __restrict__ mean_spk, const float* __restrict__ rw,
                         const float* __restrict__ rb, const float* __restrict__ rg,
                         const float* __restrict__ rbe, float* __restrict__ combine) {
    int n = threadIdx.x;
    if (n >= NN) return;
    float l[EE];
    #pragma unroll
    for (int e = 0; e < EE; ++e) {
        float acc = 0.f;
        for (int c = 0; c < CC; ++c)
            acc = fmaf(mean_spk[n * CC + c], rw[e * CC + c], acc);
        l[e] = (acc + rb[e]) * (rg[e] * RSQ) + rbe[e];
    }
    float m = l[0];
    #pragma unroll
    for (int e = 1; e < EE; ++e) m = fmaxf(m, l[e]);
    float pr[EE], s = 0.f;
    #pragma unroll
    for (int e = 0; e < EE; ++e) { pr[e] = expf(l[e] - m); s += pr[e]; }
    #pragma unroll
    for (int e = 0; e < EE; ++e) pr[e] = pr[e] / s;
    int i1 = 0; float v1 = pr[0];
    #pragma unroll
    for (int e = 1; e < EE; ++e) { if (pr[e] > v1) { v1 = pr[e]; i1 = e; } }
    int i2 = (i1 == 0) ? 1 : 0; float v2 = (i1 == 0) ? pr[1] : pr[0];
    #pragma unroll
    for (int e = 0; e < EE; ++e) { if (e != i1 && pr[e] > v2) { v2 = pr[e]; i2 = e; } }
    float wsum = v1 + v2;
    float wa = v1 / wsum, wb2 = v2 / wsum;
    #pragma unroll
    for (int e = 0; e < EE; ++e)
        combine[n * EE + e] = (e == i1) ? wa : ((e == i2) ? wb2 : 0.f);
}

// ---------------- unpack: 8 packed spike bytes -> short8 bf16 frag ----------------
// BIT selects expert bit (0 or 1) in each byte.
template <int BIT>
static __device__ __forceinline__ short8 unpack8(unsigned d0, unsigned d1) {
    const unsigned am = 0x00010001u << BIT;
    const unsigned mu = 0x3F80u >> BIT;
    union { unsigned u[4]; short8 s; } cv;
    unsigned t;
    t = __builtin_amdgcn_perm(0u, d0, 0x0C010C00u) & am; cv.u[0] = t * mu;
    t = __builtin_amdgcn_perm(0u, d0, 0x0C030C02u) & am; cv.u[1] = t * mu;
    t = __builtin_amdgcn_perm(0u, d1, 0x0C010C00u) & am; cv.u[2] = t * mu;
    t = __builtin_amdgcn_perm(0u, d1, 0x0C030C02u) & am; cv.u[3] = t * mu;
    return cv.s;
}

// ---------------- Kernel 3: experts via MFMA, LDS-staged spikes ----------------
// mfma_f32_16x16x32_bf16: A[i][k]: i=lane%16, k=8*(lane/16)+j; D[i][j]: j=lane%16, i=4*(lane/16)+r.
template <int BSEL>
static __device__ __forceinline__ void run_expert(
    const float* __restrict__ xn, const unsigned short* __restrict__ wbe,
    const float* __restrict__ f1e, const float* __restrict__ f2e,
    float tau, int P0, int l16, int g,
    const unsigned char* __restrict__ s1w,   // [64 px][72] packed spike bytes (both experts)
    unsigned char* __restrict__ s2w,         // [64 px][72] wave-private s2 bytes
    f32x4 (&acc)[4][4])
{
    #pragma unroll
    for (int tm = 0; tm < 4; ++tm)
        #pragma unroll
        for (int tn = 0; tn < 4; ++tn)
            acc[tm][tn] = (f32x4){0.f, 0.f, 0.f, 0.f};

    // ---- conv1: A from s1 LDS bytes ----
    #pragma unroll
    for (int ks = 0; ks < 2; ++ks) {
        short8 bfr[4];
        #pragma unroll
        for (int tn = 0; tn < 4; ++tn)
            bfr[tn] = *(const short8*)(wbe + ((l16 + 16 * tn) * 64 + ks * 32 + g * 8));
        #pragma unroll
        for (int tm = 0; tm < 4; ++tm) {
            const unsigned* mp = (const unsigned*)(s1w + (tm * 16 + l16) * 72 + ks * 32 + g * 8);
            short8 a = unpack8<BSEL>(mp[0], mp[1]);
            #pragma unroll
            for (int tn = 0; tn < 4; ++tn)
                acc[tm][tn] = __builtin_amdgcn_mfma_f32_16x16x32_bf16(a, bfr[tn], acc[tm][tn], 0, 0, 0);
        }
    }

    // ---- bias, x2 threshold -> s2 bytes; fold f1+f2 into acc ----
    #pragma unroll
    for (int tn = 0; tn < 4; ++tn) {
        int ch = l16 + 16 * tn;
        float f1v = f1e[ch];
        float f2v = f2e[ch];
        #pragma unroll
        for (int tm = 0; tm < 4; ++tm) {
            int pxl = tm * 16 + g * 4;
            f32x4 xv = *(const f32x4*)(xn + (size_t)ch * PP + (P0 + pxl));
            #pragma unroll
            for (int r = 0; r < 4; ++r) {
                float bnh = acc[tm][tn][r] + f1v;
                float x2 = xv[r] + bnh;
                s2w[(pxl + r) * 72 + ch] = (x2 >= tau) ? (unsigned char)1 : (unsigned char)0;
                acc[tm][tn][r] = bnh + f2v;
            }
        }
    }

    // ---- conv2: A from s2 LDS bytes ----
    #pragma unroll
    for (int ks = 0; ks < 2; ++ks) {
        short8 bfr[4];
        #pragma unroll
        for (int tn = 0; tn < 4; ++tn)
            bfr[tn] = *(const short8*)(wbe + 4096 + ((l16 + 16 * tn) * 64 + ks * 32 + g * 8));
        #pragma unroll
        for (int tm = 0; tm < 4; ++tm) {
            const unsigned* mp = (const unsigned*)(s2w + (tm * 16 + l16) * 72 + ks * 32 + g * 8);
            short8 a = unpack8<0>(mp[0], mp[1]);
            #pragma unroll
            for (int tn = 0; tn < 4; ++tn)
                acc[tm][tn] = __builtin_amdgcn_mfma_f32_16x16x32_bf16(a, bfr[tn], acc[tm][tn], 0, 0, 0);
        }
    }
}

__global__ void __launch_bounds__(256) k_experts(
    const float* __restrict__ x, const float* __restrict__ combine,
    const unsigned short* __restrict__ wb,
    const float* __restrict__ fb1, const float* __restrict__ fb2,
    float* __restrict__ out)
{
    __shared__ unsigned char s1p[256 * 72];     // 18432 B: packed s1 (bit0=e1, bit1=e2)
    __shared__ unsigned char s2p[4][64 * 72];   // 18432 B: per-wave s2

    int blk = blockIdx.x;
    int n = blk >> 2;
    int chunk = blk & 3;
    int tid = threadIdx.x;
    int wv = tid >> 6;
    int lane = tid & 63;
    int l16 = lane & 15;
    int g = lane >> 4;
    int P0c = chunk << 8;            // chunk pixel base
    int P0 = P0c + (wv << 6);        // wave pixel base

    const float* __restrict__ xn = x + (size_t)n * (CC * PP);

    // uniform top-2 expert scan
    int e1 = -1, e2 = -1; float wAv = 0.f, wBv = 0.f;
    #pragma unroll
    for (int e = 0; e < EE; ++e) {
        float w = combine[n * EE + e];
        bool nz = (w != 0.f);
        if (nz && e1 < 0) { e1 = e; wAv = w; }
        else if (nz && e2 < 0) { e2 = e; wBv = w; }
    }
    if (e1 < 0) { e1 = 0; wAv = 0.f; }
    if (e2 < 0) { e2 = (e1 == 0) ? 1 : 0; wBv = 0.f; }
    e1 = __builtin_amdgcn_readfirstlane(e1);
    e2 = __builtin_amdgcn_readfirstlane(e2);
    wAv = rfl_f(wAv); wBv = rfl_f(wBv);
    float tauA = (float)(1.5 + 2.5 * (double)e1 / 7.0);
    float tauB = (float)(1.5 + 2.5 * (double)e2 / 7.0);
    float wsum1 = 1.f + wAv + wBv;

    // ---- stage: coalesced x pass -> packed spike bytes in LDS ----
    // thread covers ch = wv+4*it, px = lane + 64*r (write stride 72B*1px -> 2-way banks)
    #pragma unroll 4
    for (int it = 0; it < 16; ++it) {
        int ch = wv + (it << 2);
        const float* xr = xn + (size_t)ch * PP + P0c;
        #pragma unroll
        for (int r = 0; r < 4; ++r) {
            float xv = xr[lane + 64 * r];
            s1p[(lane + 64 * r) * 72 + ch] =
                (unsigned char)((xv >= tauA ? 1 : 0) | (xv >= tauB ? 2 : 0));
        }
    }
    __syncthreads();

    const unsigned char* s1w = s1p + (size_t)(wv * 64) * 72;
    unsigned char* s2w = &s2p[wv][0];

    f32x4 accA[4][4], accB[4][4];
    run_expert<0>(xn, wb + e1 * 8192, fb1 + e1 * 64, fb2 + e1 * 64,
                  tauA, P0, l16, g, s1w, s2w, accA);
    run_expert<1>(xn, wb + e2 * 8192, fb1 + e2 * 64, fb2 + e2 * 64,
                  tauB, P0, l16, g, s1w, s2w, accB);

    // ---- final: out = x*(1+wA+wB) + wA*accA + wB*accB ----
    float* __restrict__ on = out + (size_t)n * (CC * PP);
    #pragma unroll
    for (int tn = 0; tn < 4; ++tn) {
        int ch = l16 + 16 * tn;
        #pragma unroll
        for (int tm = 0; tm < 4; ++tm) {
            int pxb = P0 + tm * 16 + g * 4;
            f32x4 xv = *(const f32x4*)(xn + (size_t)ch * PP + pxb);
            f32x4 o;
            #pragma unroll
            for (int r = 0; r < 4; ++r)
                o[r] = fmaf(xv[r], wsum1, fmaf(wAv, accA[tm][tn][r], wBv * accB[tm][tn][r]));
            *(f32x4*)(on + (size_t)ch * PP + pxb) = o;
        }
    }
}

extern "C" void kernel_launch(void* const* d_in, const int* in_sizes, int n_in,
                              void* d_out, int out_size, void* d_ws, size_t ws_size,
                              hipStream_t stream) {
    const float* x   = (const float*)d_in[0];
    const float* w1  = (const float*)d_in[1];
    const float* b1  = (const float*)d_in[2];
    const float* g1  = (const float*)d_in[3];
    const float* be1 = (const float*)d_in[4];
    const float* w2  = (const float*)d_in[5];
    const float* b2  = (const float*)d_in[6];
    const float* g2  = (const float*)d_in[7];
    const float* be2 = (const float*)d_in[8];
    const float* rw  = (const float*)d_in[9];
    const float* rb  = (const float*)d_in[10];
    const float* rg  = (const float*)d_in[11];
    const float* rbe = (const float*)d_in[12];
    float* out = (float*)d_out;
    float* ws  = (float*)d_ws;

    float* mean_spk     = ws;               // 16384 floats
    float* combine      = ws + 16384;       // 2048
    unsigned short* wb  = (unsigned short*)(ws + 18432);  // 65536 ushorts
    float* fb1          = ws + 51200;       // 512
    float* fb2          = ws + 51712;       // 512

    hipLaunchKernelGGL(k_router_lif, dim3(BB * CC), dim3(256), 0, stream, x, mean_spk);
    hipLaunchKernelGGL(k_prep, dim3(128), dim3(256), 0, stream,
                       w1, b1, g1, be1, w2, b2, g2, be2, wb, fb1, fb2);
    hipLaunchKernelGGL(k_router, dim3(1), dim3(256), 0, stream,
                       mean_spk, rw, rb, rg, rbe, combine);
    hipLaunchKernelGGL(k_experts, dim3(NN * 4), dim3(256), 0, stream,
                       x, combine, wb, fb1, fb2, out);
}